// Round 20
// baseline (131.483 us; speedup 1.0000x reference)
//
#include <hip/hip_runtime.h>
#include <hip/hip_bf16.h>

// PhaseSynchronizedAttention: B=2 S=2048 D=1024 H=16 DK=64, fp32 in/out.
// Round 20: R19's manual pipeline reverted (sched_barrier pinning defeated
// the compiler, m141-style). Back to R18's schedule; k_gemm M-tile 128->64:
// grid (8,64,3)=1536 blocks = 6/CU (was 3/CU) -- latency hidden by TLP.
// gemm1/attn/splitW identical to R18.

typedef short bf16x8 __attribute__((ext_vector_type(8)));
typedef float f32x4 __attribute__((ext_vector_type(4)));
typedef unsigned short u16;
typedef unsigned short u16x8 __attribute__((ext_vector_type(8)));
typedef unsigned short u16x4 __attribute__((ext_vector_type(4)));

static __device__ __forceinline__ u16 f2bf(float x) {
    __hip_bfloat16 b = __float2bfloat16(x);
    return *reinterpret_cast<u16*>(&b);
}
static __device__ __forceinline__ bf16x8 g8(const u16* p) {
    return *reinterpret_cast<const bf16x8*>(p);
}
static __device__ __forceinline__ float fast_exp2(float x) {
#if __has_builtin(__builtin_amdgcn_exp2f)
    return __builtin_amdgcn_exp2f(x);
#else
    return exp2f(x);
#endif
}
static __device__ __forceinline__ void gl16(const u16* g, u16* l) {
    __builtin_amdgcn_global_load_lds(
        (const __attribute__((address_space(1))) void*)g,
        (__attribute__((address_space(3))) void*)l, 16, 0, 0);
}
static __device__ __forceinline__ u16x8 cvt8(const float4& a, const float4& b) {
    u16x8 r;
    r[0] = f2bf(a.x); r[1] = f2bf(a.y); r[2] = f2bf(a.z); r[3] = f2bf(a.w);
    r[4] = f2bf(b.x); r[5] = f2bf(b.y); r[6] = f2bf(b.z); r[7] = f2bf(b.w);
    return r;
}

// swizzled LDS read offset for [*][32] u16 tiles (conflict-free b128).
#define SWZ(row, col) ((row) * 32 + ((col) ^ ((((row) >> 1) & 3) << 3)))

// ---------------- weight split (hi-only): grid (1024, 4) ----------------
__global__ void k_splitW(const float* __restrict__ w0, const float* __restrict__ w1,
                         const float* __restrict__ w2, const float* __restrict__ w3,
                         u16* __restrict__ h0, u16* __restrict__ h1,
                         u16* __restrict__ h2, u16* __restrict__ h3) {
    const int i = blockIdx.x * 256 + threadIdx.x;  // < 262144 float4s
    const float* s;
    u16* H;
    if (blockIdx.y == 0) { s = w0; H = h0; }
    else if (blockIdx.y == 1) { s = w1; H = h1; }
    else if (blockIdx.y == 2) { s = w2; H = h2; }
    else { s = w3; H = h3; }
    float4 val = reinterpret_cast<const float4*>(s)[i];
    u16x4 h;
    h[0] = f2bf(val.x); h[1] = f2bf(val.y);
    h[2] = f2bf(val.z); h[3] = f2bf(val.w);
    reinterpret_cast<u16x4*>(H)[i] = h;
}

// ---------------- QKV GEMM (1-term, hybrid staging, 64x128 tile) ----------
// z: 0=Q-proj(rotate, scale incl. log2e, hi out), 1=K-proj(rotate, hi out),
// 2=V-proj(fused transpose -> V^T bf16). grid (8,64,3); XCD swizzle.
// Waves 2x2: wave (wr,wc) owns rows wr*32..+32, cols wc*64..+64 (full head).
__global__ __launch_bounds__(256) void k_gemm(
    const float* __restrict__ qf, const float* __restrict__ kf,
    const float* __restrict__ vf,
    const u16* __restrict__ Wqh, const u16* __restrict__ Wkh,
    const u16* __restrict__ Wvh,
    const float* __restrict__ bq, const float* __restrict__ bk,
    const float* __restrict__ bv_,
    const float* __restrict__ phase,
    u16* __restrict__ Qrh, u16* __restrict__ Krh,
    u16* __restrict__ VTh) {
    __shared__ __attribute__((aligned(16))) u16 sA0[64 * 32];
    __shared__ __attribute__((aligned(16))) u16 sA1[64 * 32];
    __shared__ __attribute__((aligned(16))) u16 sB0[128 * 32];
    __shared__ __attribute__((aligned(16))) u16 sB1[128 * 32];

    const int z = blockIdx.z;
    const float* Af;
    const u16* Bh;
    const float* bias;
    if (z == 0) { Af = qf; Bh = Wqh; bias = bq; }
    else if (z == 1) { Af = kf; Bh = Wkh; bias = bk; }
    else { Af = vf; Bh = Wvh; bias = bv_; }

    const int flat = blockIdx.y * 8 + blockIdx.x;           // 0..511
    const int tau = (flat & 7) * 64 + (flat >> 3);          // bijective
    const int bx = tau & 7, by = tau >> 3;

    const int t = threadIdx.x;
    const int l = t & 63, w = t >> 6;
    const int wr = w >> 1, wc = w & 1;
    const int m0 = by * 64, n0 = bx * 128;
    const int fr = l & 15;
    const int fk = (l >> 4) * 8;
    const int ar = wr * 32 + fr;
    const int br = wc * 64 + fr;

    // B staging (gload_lds, source-side swizzle) — proven map
    const int grow = w * 32 + (l >> 2);
    const int colx = ((l & 3) * 8) ^ (((grow >> 1) & 3) << 3);
    const int lb0 = w * 1024, lb1 = w * 1024 + 512;
    const u16* pB0 = Bh + (size_t)(n0 + grow) * 1024 + colx;
    const u16* pB1 = Bh + (size_t)(n0 + grow + 16) * 1024 + colx;

    // A staging (fp32 regs -> cvt -> swizzled ds_write), 64 rows
    const int srow = t >> 2;            // 0..63
    const int scol = (t & 3) * 8;
    const float* pAr = Af + (size_t)(m0 + srow) * 1024 + scol;
    const int so0 = SWZ(srow, scol);

    float4 a0_0, a0_1;                  // reg set 0
    float4 a1_0, a1_1;                  // reg set 1
    auto loadA0 = [&](int kk) {
        const int ko = kk * 32;
        a0_0 = *reinterpret_cast<const float4*>(pAr + ko);
        a0_1 = *reinterpret_cast<const float4*>(pAr + ko + 4);
    };
    auto loadA1 = [&](int kk) {
        const int ko = kk * 32;
        a1_0 = *reinterpret_cast<const float4*>(pAr + ko);
        a1_1 = *reinterpret_cast<const float4*>(pAr + ko + 4);
    };
    auto writeA0 = [&](u16* SA) {
        *reinterpret_cast<u16x8*>(&SA[so0]) = cvt8(a0_0, a0_1);
    };
    auto writeA1 = [&](u16* SA) {
        *reinterpret_cast<u16x8*>(&SA[so0]) = cvt8(a1_0, a1_1);
    };
    auto stageB = [&](u16* SB, int kk) {
        const int ko = kk * 32;
        gl16(pB0 + ko, &SB[lb0]);
        gl16(pB1 + ko, &SB[lb1]);
    };

    f32x4 acc[2][4];
#pragma unroll
    for (int m = 0; m < 2; ++m)
#pragma unroll
        for (int n = 0; n < 4; ++n) acc[m][n] = (f32x4){0.f, 0.f, 0.f, 0.f};

    auto compute = [&](const u16* SA, const u16* SB) {
        bf16x8 fa[2], fb[4];
#pragma unroll
        for (int m = 0; m < 2; ++m)
            fa[m] = *reinterpret_cast<const bf16x8*>(&SA[SWZ(ar + m * 16, fk)]);
#pragma unroll
        for (int n = 0; n < 4; ++n)
            fb[n] = *reinterpret_cast<const bf16x8*>(&SB[SWZ(br + n * 16, fk)]);
#pragma unroll
        for (int m = 0; m < 2; ++m)
#pragma unroll
            for (int n = 0; n < 4; ++n)
                acc[m][n] = __builtin_amdgcn_mfma_f32_16x16x32_bf16(fa[m], fb[n], acc[m][n], 0, 0, 0);
    };

    // prologue (R18 schedule)
    loadA0(0);
    stageB(sB0, 0);
    writeA0(sA0);
    __syncthreads();

    for (int kk = 0; kk < 32; kk += 2) {
        loadA1(kk + 1);
        stageB(sB1, kk + 1);
        compute(sA0, sB0);
        writeA1(sA1);
        __syncthreads();
        const bool more = (kk + 2 < 32);
        if (more) {
            loadA0(kk + 2);
            stageB(sB0, kk + 2);
        }
        compute(sA1, sB1);
        if (more) writeA0(sA0);
        __syncthreads();
    }

    const int er4 = (l >> 4) * 4;
    float bvv[4];
#pragma unroll
    for (int n = 0; n < 4; ++n) bvv[n] = bias[n0 + wc * 64 + n * 16 + fr];

    if (z == 2) {
        // fused transpose: V^T[(b*16+h)*64+d][s], 4 consecutive s per thread
#pragma unroll
        for (int m = 0; m < 2; ++m) {
            const int row0 = m0 + wr * 32 + m * 16 + er4;  // s-base (mult of 4)
            const int bb = row0 >> 11;
            const int ss = row0 & 2047;
#pragma unroll
            for (int n = 0; n < 4; ++n) {
                const int col = n0 + wc * 64 + n * 16 + fr;
                const int hh_ = col >> 6, dd = col & 63;
                u16x4 vv;
#pragma unroll
                for (int r = 0; r < 4; ++r) vv[r] = f2bf(acc[m][n][r] + bvv[n]);
                *reinterpret_cast<u16x4*>(
                    &VTh[((size_t)(bb * 16 + hh_) * 64 + dd) * 2048 + ss]) = vv;
            }
        }
    } else {
        // bias + phase rotation + scale + bf16 (hi-only) store.
        u16* Dh = z ? Krh : Qrh;
        const float sc = z ? 1.0f : 0.18033688011112042f;  // (1/8)*log2(e)
        const int head = bx * 2 + wc;
        float sv, cv;
        sincosf(phase[head], &sv, &cv);
#pragma unroll
        for (int m = 0; m < 2; ++m)
#pragma unroll
            for (int n = 0; n < 2; ++n) {
#pragma unroll
                for (int r = 0; r < 4; ++r) {
                    const float xr = acc[m][n][r] + bvv[n];
                    const float xi = acc[m][n + 2][r] + bvv[n + 2];
                    const float o0 = (xr * cv - xi * sv) * sc;
                    const float o1 = (xr * sv + xi * cv) * sc;
                    const int row = m0 + wr * 32 + m * 16 + er4 + r;
                    const size_t i0 = (size_t)row * 1024 + head * 64 + n * 16 + fr;
                    Dh[i0] = f2bf(o0);
                    Dh[i0 + 32] = f2bf(o1);
                }
            }
    }
}

// ---------------- out-proj GEMM (1-term, full gload_lds; R18 form) --------
__global__ __launch_bounds__(256) void k_gemm1(
    const u16* __restrict__ Ah, const u16* __restrict__ Bh,
    const float* __restrict__ bias, float* __restrict__ C) {
    __shared__ __attribute__((aligned(16))) u16 sA0[128 * 32];
    __shared__ __attribute__((aligned(16))) u16 sA1[128 * 32];
    __shared__ __attribute__((aligned(16))) u16 sB0[128 * 32];
    __shared__ __attribute__((aligned(16))) u16 sB1[128 * 32];

    const int flat = blockIdx.y * 8 + blockIdx.x;           // 0..255
    const int tau = (flat & 7) * 32 + (flat >> 3);          // bijective
    const int bx = tau & 7, by = tau >> 3;

    const int t = threadIdx.x;
    const int l = t & 63, w = t >> 6;
    const int wr = w >> 1, wc = w & 1;
    const int m0 = by * 128, n0 = bx * 128;
    const int fr = l & 15;
    const int fk = (l >> 4) * 8;
    const int ar = wr * 64 + fr;
    const int br = wc * 64 + fr;

    const int grow = w * 32 + (l >> 2);
    const int colx = ((l & 3) * 8) ^ (((grow >> 1) & 3) << 3);
    const int lb0 = w * 1024, lb1 = w * 1024 + 512;
    const u16* pA0 = Ah + (size_t)(m0 + grow) * 1024 + colx;
    const u16* pA1 = Ah + (size_t)(m0 + grow + 16) * 1024 + colx;
    const u16* pB0 = Bh + (size_t)(n0 + grow) * 1024 + colx;
    const u16* pB1 = Bh + (size_t)(n0 + grow + 16) * 1024 + colx;

    auto stage = [&](u16* SA, u16* SB, int kk) {
        const int ko = kk * 32;
        gl16(pA0 + ko, &SA[lb0]);
        gl16(pA1 + ko, &SA[lb1]);
        gl16(pB0 + ko, &SB[lb0]);
        gl16(pB1 + ko, &SB[lb1]);
    };

    f32x4 acc[4][4];
#pragma unroll
    for (int m = 0; m < 4; ++m)
#pragma unroll
        for (int n = 0; n < 4; ++n) acc[m][n] = (f32x4){0.f, 0.f, 0.f, 0.f};

    auto compute = [&](const u16* SA, const u16* SB) {
        bf16x8 fa[4], fb[4];
#pragma unroll
        for (int m = 0; m < 4; ++m)
            fa[m] = *reinterpret_cast<const bf16x8*>(&SA[SWZ(ar + m * 16, fk)]);
#pragma unroll
        for (int n = 0; n < 4; ++n)
            fb[n] = *reinterpret_cast<const bf16x8*>(&SB[SWZ(br + n * 16, fk)]);
#pragma unroll
        for (int m = 0; m < 4; ++m)
#pragma unroll
            for (int n = 0; n < 4; ++n)
                acc[m][n] = __builtin_amdgcn_mfma_f32_16x16x32_bf16(fa[m], fb[n], acc[m][n], 0, 0, 0);
    };

    stage(sA0, sB0, 0);
    __syncthreads();
    for (int kk = 0; kk < 32; kk += 2) {
        stage(sA1, sB1, kk + 1);
        compute(sA0, sB0);
        __syncthreads();
        if (kk + 2 < 32) stage(sA0, sB0, kk + 2);
        compute(sA1, sB1);
        __syncthreads();
    }

    const int er4 = (l >> 4) * 4;
    float bvv[4];
#pragma unroll
    for (int n = 0; n < 4; ++n) bvv[n] = bias[n0 + wc * 64 + n * 16 + fr];
#pragma unroll
    for (int m = 0; m < 4; ++m)
#pragma unroll
        for (int n = 0; n < 4; ++n) {
            const int col = n0 + wc * 64 + n * 16 + fr;
            const size_t rb = (size_t)(m0 + wr * 64 + m * 16 + er4) * 1024 + col;
#pragma unroll
            for (int r = 0; r < 4; ++r) C[rb + (size_t)r * 1024] = acc[m][n][r] + bvv[n];
        }
}

// ---------------- flash attention (frozen from R16/R17/R18) ---------------
#define SM_M2 17.312340490667562f  // 12 * log2(e)

#define ATTN_TILE(SK, SV)                                                      \
  {                                                                            \
    f32x4 s[2][4];                                                             \
    _Pragma("unroll") for (int qm = 0; qm < 2; ++qm)                           \
      _Pragma("unroll") for (int n = 0; n < 4; ++n)                            \
        s[qm][n] = (f32x4){-SM_M2, -SM_M2, -SM_M2, -SM_M2};                    \
    _Pragma("unroll") for (int n = 0; n < 4; ++n)                              \
      _Pragma("unroll") for (int ks = 0; ks < 2; ++ks) {                       \
        bf16x8 bkh = *reinterpret_cast<const bf16x8*>(                         \
            &SK[(n * 16 + fr) * 64 + ((ks * 32 + fk) ^ rswz)]);                \
        _Pragma("unroll") for (int qm = 0; qm < 2; ++qm)                       \
          s[qm][n] = __builtin_amdgcn_mfma_f32_16x16x32_bf16(aqh[qm][ks], bkh, s[qm][n], 0, 0, 0); \
      }                                                                        \
    _Pragma("unroll") for (int qm = 0; qm < 2; ++qm)                           \
      _Pragma("unroll") for (int n = 0; n < 4; ++n)                            \
        _Pragma("unroll") for (int r = 0; r < 4; ++r) {                        \
          const float p = fast_exp2(s[qm][n][r]);                              \
          const int prow = w * 32 + qm * 16 + (l >> 4) * 4 + r;                \
          const int pcol = (n * 16 + (l & 15)) ^ ((prow & 7) << 3);            \
          sPh[prow * 64 + pcol] = f2bf(p);                                     \
        }                                                                      \
    bf16x8 bph[2][2];                                                          \
    _Pragma("unroll") for (int qm = 0; qm < 2; ++qm)                           \
      _Pragma("unroll") for (int ks = 0; ks < 2; ++ks)                         \
        bph[qm][ks] = *reinterpret_cast<const bf16x8*>(                        \
            &sPh[(w * 32 + qm * 16 + fr) * 64 + ((ks * 32 + fk) ^ rswz)]);     \
    _Pragma("unroll") for (int m = 0; m < 4; ++m)                              \
      _Pragma("unroll") for (int ks = 0; ks < 2; ++ks) {                       \
        bf16x8 avh = *reinterpret_cast<const bf16x8*>(                         \
            &SV[(m * 16 + fr) * 64 + ((ks * 32 + fk) ^ rswz)]);                \
        _Pragma("unroll") for (int qm = 0; qm < 2; ++qm)                       \
          aco[qm][m] = __builtin_amdgcn_mfma_f32_16x16x32_bf16(avh, bph[qm][ks], aco[qm][m], 0, 0, 0); \
      }                                                                        \
    _Pragma("unroll") for (int qm = 0; qm < 2; ++qm)                           \
      _Pragma("unroll") for (int ks = 0; ks < 2; ++ks)                         \
        acl[qm] = __builtin_amdgcn_mfma_f32_16x16x32_bf16(vone, bph[qm][ks], acl[qm], 0, 0, 0); \
  }

#define ATTN_STAGE(SK, SV)                                                     \
  {                                                                            \
    _Pragma("unroll") for (int i = 0; i < 2; ++i) {                            \
      *reinterpret_cast<bf16x8*>(&SK[soff[i]]) = rKh[i];                       \
      *reinterpret_cast<bf16x8*>(&SV[soff[i]]) = rVh[i];                       \
    }                                                                          \
  }

__global__ __launch_bounds__(256) void k_attn(
    const u16* __restrict__ Qh,
    const u16* __restrict__ Kh,
    const u16* __restrict__ VTh,
    u16* __restrict__ AOh) {
    __shared__ __attribute__((aligned(16))) u16 sK0[4096];
    __shared__ __attribute__((aligned(16))) u16 sK1[4096];
    __shared__ __attribute__((aligned(16))) u16 sV0[4096];
    __shared__ __attribute__((aligned(16))) u16 sV1[4096];
    __shared__ __attribute__((aligned(16))) u16 sPh[128 * 64];

    const int t = threadIdx.x;
    const int l = t & 63, w = t >> 6;
    const int flat = blockIdx.y * 16 + blockIdx.x;          // 0..511
    const int tau = (flat & 7) * 64 + (flat >> 3);          // bijective
    const int q0 = (tau & 15) * 128;
    const int bh = tau >> 4;
    const int b = bh >> 4, h = bh & 15;
    const size_t qrow0 = (size_t)b * 2048 + q0;

    const u16* Qb_h = Qh + qrow0 * 1024 + h * 64;
    const u16* Kb_h = Kh + (size_t)b * 2048 * 1024 + h * 64;
    const u16* Vb_h = VTh + (size_t)bh * 64 * 2048;

    const int fr = l & 15;
    const int fk = (l >> 4) * 8;

    bf16x8 aqh[2][2];
#pragma unroll
    for (int qm = 0; qm < 2; ++qm)
#pragma unroll
        for (int ks = 0; ks < 2; ++ks) {
            const size_t qo = (size_t)(w * 32 + qm * 16 + fr) * 1024 + ks * 32 + fk;
            aqh[qm][ks] = g8(Qb_h + qo);
        }

    bf16x8 vone;
#pragma unroll
    for (int j = 0; j < 8; ++j) vone[j] = (short)0x3F80;

    f32x4 aco[2][4];
    f32x4 acl[2];
#pragma unroll
    for (int qm = 0; qm < 2; ++qm) {
        acl[qm] = (f32x4){0.f, 0.f, 0.f, 0.f};
#pragma unroll
        for (int m = 0; m < 4; ++m) aco[qm][m] = (f32x4){0.f, 0.f, 0.f, 0.f};
    }

    const int sr = t >> 3, sc = (t & 7) * 8;  // staging: row sr(+32), col sc
    bf16x8 rKh[2], rVh[2];
    auto load_kv = [&](int tt) {
        const int kv0 = tt * 64;
#pragma unroll
        for (int i = 0; i < 2; ++i) {
            const int r2 = sr + i * 32;
            rKh[i] = g8(Kb_h + (size_t)(kv0 + r2) * 1024 + sc);
            rVh[i] = g8(Vb_h + (size_t)r2 * 2048 + kv0 + sc);
        }
    };
    int soff[2];
#pragma unroll
    for (int i = 0; i < 2; ++i) {
        const int r2 = sr + i * 32;
        soff[i] = r2 * 64 + (sc ^ ((r2 & 7) << 3));
    }
    const int rswz = (fr & 7) << 3;

    load_kv(0);
    ATTN_STAGE(sK0, sV0);
    __syncthreads();

    for (int tt = 0; tt < 32; tt += 2) {
        load_kv(tt + 1);
        ATTN_TILE(sK0, sV0);
        ATTN_STAGE(sK1, sV1);
        __syncthreads();
        if (tt + 2 < 32) load_kv(tt + 2);
        ATTN_TILE(sK1, sV1);
        if (tt + 2 < 32) ATTN_STAGE(sK0, sV0);
        __syncthreads();
    }

#pragma unroll
    for (int qm = 0; qm < 2; ++qm) {
        const float inv = 1.0f / acl[qm][0];
#pragma unroll
        for (int m = 0; m < 4; ++m) aco[qm][m] *= inv;
    }

    // wave-private transpose through the wave's own dead 8KB K/V buffer.
    float* Ol = reinterpret_cast<float*>(
        (w == 0) ? sK0 : (w == 1) ? sK1 : (w == 2) ? sV0 : sV1);
#pragma unroll
    for (int qm = 0; qm < 2; ++qm) {
        const int qr = qm * 16 + (l & 15);
        const int sw = (qr & 7) << 3;
#pragma unroll
        for (int m = 0; m < 4; ++m)
#pragma unroll
            for (int r = 0; r < 4; ++r)
                Ol[qr * 64 + ((m * 16 + (l >> 4) * 4 + r) ^ sw)] = aco[qm][m][r];
    }
#pragma unroll
    for (int it = 0; it < 4; ++it) {
        const int qr = (l >> 3) + it * 8;   // 0..31 within the wave's rows
        const int cb = (l & 7) * 8;
        const int sw = (qr & 7) << 3;
        const float* srcp = &Ol[qr * 64 + (cb ^ sw)];
        u16x8 oh;
#pragma unroll
        for (int j = 0; j < 8; ++j) oh[j] = f2bf(srcp[j]);
        const size_t ob = (qrow0 + w * 32 + qr) * 1024 + h * 64 + cb;
        *reinterpret_cast<u16x8*>(&AOh[ob]) = oh;
    }
}

// ---------------- host ----------------
extern "C" void kernel_launch(void* const* d_in, const int* in_sizes, int n_in,
                              void* d_out, int out_size, void* d_ws, size_t ws_size,
                              hipStream_t stream) {
    const float* q = (const float*)d_in[0];
    const float* k = (const float*)d_in[1];
    const float* v = (const float*)d_in[2];
    const float* Wq = (const float*)d_in[3];
    const float* bq = (const float*)d_in[4];
    const float* Wk = (const float*)d_in[5];
    const float* bk = (const float*)d_in[6];
    const float* Wv = (const float*)d_in[7];
    const float* bv = (const float*)d_in[8];
    const float* Wo = (const float*)d_in[9];
    const float* bo = (const float*)d_in[10];
    const float* phase = (const float*)d_in[11];
    float* out = (float*)d_out;

    char* ws = (char*)d_ws;
    const size_t MB = 1u << 20;
    u16* Wq_h = (u16*)(ws + 0 * MB);
    u16* Wk_h = (u16*)(ws + 2 * MB);
    u16* Wv_h = (u16*)(ws + 4 * MB);
    u16* Wo_h = (u16*)(ws + 6 * MB);
    u16* QR_h = (u16*)(ws + 64 * MB);
    u16* KR_h = (u16*)(ws + 80 * MB);
    u16* VT_h = (u16*)(ws + 96 * MB);
    u16* AO_h = (u16*)(ws + 16 * MB);

    // 1. weight split (small)
    k_splitW<<<dim3(1024, 4), 256, 0, stream>>>(Wq, Wk, Wv, Wo,
                                                Wq_h, Wk_h, Wv_h, Wo_h);
    // 2. fused QKV projections; 64x128 tiles, 6 blocks/CU
    k_gemm<<<dim3(8, 64, 3), 256, 0, stream>>>(
        q, k, v, Wq_h, Wk_h, Wv_h,
        bq, bk, bv, phase, QR_h, KR_h, VT_h);
    // 3. attention (QBLK=128)
    k_attn<<<dim3(16, 32), 256, 0, stream>>>(QR_h, KR_h, VT_h, AO_h);
    // 4. output projection (1-term, R18 form)
    k_gemm1<<<dim3(8, 32), 256, 0, stream>>>(AO_h, Wo_h, bo, out);
    (void)in_sizes; (void)n_in; (void)out_size; (void)ws_size;
}

// Round 21
// 124.226 us; speedup vs baseline: 1.0584x; 1.0584x over previous
//
#include <hip/hip_runtime.h>
#include <hip/hip_bf16.h>

// PhaseSynchronizedAttention: B=2 S=2048 D=1024 H=16 DK=64, fp32 in/out.
// Round 21: exact revert to R18 (best measured: 124.4us). R19 (counted
// vmcnt) and R20 (smaller tile / more TLP) both regressed and refuted
// their theories; banking the best-known configuration.

typedef short bf16x8 __attribute__((ext_vector_type(8)));
typedef float f32x4 __attribute__((ext_vector_type(4)));
typedef unsigned short u16;
typedef unsigned short u16x8 __attribute__((ext_vector_type(8)));
typedef unsigned short u16x4 __attribute__((ext_vector_type(4)));

static __device__ __forceinline__ u16 f2bf(float x) {
    __hip_bfloat16 b = __float2bfloat16(x);
    return *reinterpret_cast<u16*>(&b);
}
static __device__ __forceinline__ bf16x8 g8(const u16* p) {
    return *reinterpret_cast<const bf16x8*>(p);
}
static __device__ __forceinline__ float fast_exp2(float x) {
#if __has_builtin(__builtin_amdgcn_exp2f)
    return __builtin_amdgcn_exp2f(x);
#else
    return exp2f(x);
#endif
}
// async global->LDS, 16 B per lane; lds ptr wave-uniform.
static __device__ __forceinline__ void gl16(const u16* g, u16* l) {
    __builtin_amdgcn_global_load_lds(
        (const __attribute__((address_space(1))) void*)g,
        (__attribute__((address_space(3))) void*)l, 16, 0, 0);
}
static __device__ __forceinline__ u16x8 cvt8(const float4& a, const float4& b) {
    u16x8 r;
    r[0] = f2bf(a.x); r[1] = f2bf(a.y); r[2] = f2bf(a.z); r[3] = f2bf(a.w);
    r[4] = f2bf(b.x); r[5] = f2bf(b.y); r[6] = f2bf(b.z); r[7] = f2bf(b.w);
    return r;
}

// swizzled LDS read offset for [128][32] u16 tiles (conflict-free b128).
#define SWZ(row, col) ((row) * 32 + ((col) ^ ((((row) >> 1) & 3) << 3)))

// ---------------- weight split (hi-only): grid (1024, 4) ----------------
__global__ void k_splitW(const float* __restrict__ w0, const float* __restrict__ w1,
                         const float* __restrict__ w2, const float* __restrict__ w3,
                         u16* __restrict__ h0, u16* __restrict__ h1,
                         u16* __restrict__ h2, u16* __restrict__ h3) {
    const int i = blockIdx.x * 256 + threadIdx.x;  // < 262144 float4s
    const float* s;
    u16* H;
    if (blockIdx.y == 0) { s = w0; H = h0; }
    else if (blockIdx.y == 1) { s = w1; H = h1; }
    else if (blockIdx.y == 2) { s = w2; H = h2; }
    else { s = w3; H = h3; }
    float4 val = reinterpret_cast<const float4*>(s)[i];
    u16x4 h;
    h[0] = f2bf(val.x); h[1] = f2bf(val.y);
    h[2] = f2bf(val.z); h[3] = f2bf(val.w);
    reinterpret_cast<u16x4*>(H)[i] = h;
}

// ---------------- QKV GEMM (1-term, hybrid staging) -----------------------
// z: 0=Q-proj(rotate, scale incl. log2e, hi out), 1=K-proj(rotate, hi out),
// 2=V-proj(fused transpose -> V^T bf16). XCD swizzle.
__global__ __launch_bounds__(256) void k_gemm(
    const float* __restrict__ qf, const float* __restrict__ kf,
    const float* __restrict__ vf,
    const u16* __restrict__ Wqh, const u16* __restrict__ Wkh,
    const u16* __restrict__ Wvh,
    const float* __restrict__ bq, const float* __restrict__ bk,
    const float* __restrict__ bv_,
    const float* __restrict__ phase,
    u16* __restrict__ Qrh, u16* __restrict__ Krh,
    u16* __restrict__ VTh) {
    __shared__ __attribute__((aligned(16))) u16 sA0[128 * 32];
    __shared__ __attribute__((aligned(16))) u16 sA1[128 * 32];
    __shared__ __attribute__((aligned(16))) u16 sB0[128 * 32];
    __shared__ __attribute__((aligned(16))) u16 sB1[128 * 32];

    const int z = blockIdx.z;
    const float* Af;
    const u16* Bh;
    const float* bias;
    if (z == 0) { Af = qf; Bh = Wqh; bias = bq; }
    else if (z == 1) { Af = kf; Bh = Wkh; bias = bk; }
    else { Af = vf; Bh = Wvh; bias = bv_; }

    const int flat = blockIdx.y * 8 + blockIdx.x;           // 0..255
    const int tau = (flat & 7) * 32 + (flat >> 3);          // bijective
    const int bx = tau & 7, by = tau >> 3;

    const int t = threadIdx.x;
    const int l = t & 63, w = t >> 6;
    const int wr = w >> 1, wc = w & 1;
    const int m0 = by * 128, n0 = bx * 128;
    const int fr = l & 15;
    const int fk = (l >> 4) * 8;
    const int ar = wr * 64 + fr;
    const int br = wc * 64 + fr;

    // B staging (gload_lds, source-side swizzle) — R17-proven map
    const int grow = w * 32 + (l >> 2);
    const int colx = ((l & 3) * 8) ^ (((grow >> 1) & 3) << 3);
    const int lb0 = w * 1024, lb1 = w * 1024 + 512;
    const u16* pB0 = Bh + (size_t)(n0 + grow) * 1024 + colx;
    const u16* pB1 = Bh + (size_t)(n0 + grow + 16) * 1024 + colx;

    // A staging (fp32 regs -> cvt -> swizzled ds_write)
    const int srow = t >> 2;
    const int scol = (t & 3) * 8;
    const float* pA0 = Af + (size_t)(m0 + srow) * 1024 + scol;
    const float* pA1 = Af + (size_t)(m0 + 64 + srow) * 1024 + scol;
    const int so0 = SWZ(srow, scol);
    const int so1 = SWZ(srow + 64, scol);

    float4 a00, a01, a10, a11;
    auto loadA = [&](int kk) {
        const int ko = kk * 32;
        a00 = *reinterpret_cast<const float4*>(pA0 + ko);
        a01 = *reinterpret_cast<const float4*>(pA0 + ko + 4);
        a10 = *reinterpret_cast<const float4*>(pA1 + ko);
        a11 = *reinterpret_cast<const float4*>(pA1 + ko + 4);
    };
    auto stageB = [&](u16* SB, int kk) {
        const int ko = kk * 32;
        gl16(pB0 + ko, &SB[lb0]);
        gl16(pB1 + ko, &SB[lb1]);
    };
    auto writeA = [&](u16* SA) {
        *reinterpret_cast<u16x8*>(&SA[so0]) = cvt8(a00, a01);
        *reinterpret_cast<u16x8*>(&SA[so1]) = cvt8(a10, a11);
    };

    f32x4 acc[4][4];
#pragma unroll
    for (int m = 0; m < 4; ++m)
#pragma unroll
        for (int n = 0; n < 4; ++n) acc[m][n] = (f32x4){0.f, 0.f, 0.f, 0.f};

    auto compute = [&](const u16* SA, const u16* SB) {
        bf16x8 fa[4], fb[4];
#pragma unroll
        for (int m = 0; m < 4; ++m)
            fa[m] = *reinterpret_cast<const bf16x8*>(&SA[SWZ(ar + m * 16, fk)]);
#pragma unroll
        for (int n = 0; n < 4; ++n)
            fb[n] = *reinterpret_cast<const bf16x8*>(&SB[SWZ(br + n * 16, fk)]);
#pragma unroll
        for (int m = 0; m < 4; ++m)
#pragma unroll
            for (int n = 0; n < 4; ++n)
                acc[m][n] = __builtin_amdgcn_mfma_f32_16x16x32_bf16(fa[m], fb[n], acc[m][n], 0, 0, 0);
    };

    // prologue
    loadA(0);
    stageB(sB0, 0);
    writeA(sA0);
    __syncthreads();

    for (int kk = 0; kk < 32; kk += 2) {
        // phase A: compute buf0; prefetch kk+1; write A late
        loadA(kk + 1);
        stageB(sB1, kk + 1);
        compute(sA0, sB0);
        writeA(sA1);
        __syncthreads();
        // phase B: compute buf1; prefetch kk+2; write A late
        const bool more = (kk + 2 < 32);
        if (more) {
            loadA(kk + 2);
            stageB(sB0, kk + 2);
        }
        compute(sA1, sB1);
        if (more) writeA(sA0);
        __syncthreads();
    }

    const int er4 = (l >> 4) * 4;
    float bvv[4];
#pragma unroll
    for (int n = 0; n < 4; ++n) bvv[n] = bias[n0 + wc * 64 + n * 16 + fr];

    if (z == 2) {
        // fused transpose: V^T[(b*16+h)*64+d][s], 4 consecutive s per thread
#pragma unroll
        for (int m = 0; m < 4; ++m) {
            const int row0 = m0 + wr * 64 + m * 16 + er4;  // s-base (mult of 4)
            const int bb = row0 >> 11;
            const int ss = row0 & 2047;
#pragma unroll
            for (int n = 0; n < 4; ++n) {
                const int col = n0 + wc * 64 + n * 16 + fr;
                const int hh_ = col >> 6, dd = col & 63;
                u16x4 vv;
#pragma unroll
                for (int r = 0; r < 4; ++r) vv[r] = f2bf(acc[m][n][r] + bvv[n]);
                *reinterpret_cast<u16x4*>(
                    &VTh[((size_t)(bb * 16 + hh_) * 64 + dd) * 2048 + ss]) = vv;
            }
        }
    } else {
        // bias + phase rotation + scale + bf16 (hi-only) store.
        u16* Dh = z ? Krh : Qrh;
        const float sc = z ? 1.0f : 0.18033688011112042f;  // (1/8)*log2(e)
        const int head = bx * 2 + wc;
        float sv, cv;
        sincosf(phase[head], &sv, &cv);
#pragma unroll
        for (int m = 0; m < 4; ++m)
#pragma unroll
            for (int n = 0; n < 2; ++n) {
#pragma unroll
                for (int r = 0; r < 4; ++r) {
                    const float xr = acc[m][n][r] + bvv[n];
                    const float xi = acc[m][n + 2][r] + bvv[n + 2];
                    const float o0 = (xr * cv - xi * sv) * sc;
                    const float o1 = (xr * sv + xi * cv) * sc;
                    const int row = m0 + wr * 64 + m * 16 + er4 + r;
                    const size_t i0 = (size_t)row * 1024 + head * 64 + n * 16 + fr;
                    Dh[i0] = f2bf(o0);
                    Dh[i0 + 32] = f2bf(o1);
                }
            }
    }
}

// ---------------- out-proj GEMM (1-term, full gload_lds; R17-proven) ------
__global__ __launch_bounds__(256) void k_gemm1(
    const u16* __restrict__ Ah, const u16* __restrict__ Bh,
    const float* __restrict__ bias, float* __restrict__ C) {
    __shared__ __attribute__((aligned(16))) u16 sA0[128 * 32];
    __shared__ __attribute__((aligned(16))) u16 sA1[128 * 32];
    __shared__ __attribute__((aligned(16))) u16 sB0[128 * 32];
    __shared__ __attribute__((aligned(16))) u16 sB1[128 * 32];

    const int flat = blockIdx.y * 8 + blockIdx.x;           // 0..255
    const int tau = (flat & 7) * 32 + (flat >> 3);          // bijective
    const int bx = tau & 7, by = tau >> 3;

    const int t = threadIdx.x;
    const int l = t & 63, w = t >> 6;
    const int wr = w >> 1, wc = w & 1;
    const int m0 = by * 128, n0 = bx * 128;
    const int fr = l & 15;
    const int fk = (l >> 4) * 8;
    const int ar = wr * 64 + fr;
    const int br = wc * 64 + fr;

    const int grow = w * 32 + (l >> 2);
    const int colx = ((l & 3) * 8) ^ (((grow >> 1) & 3) << 3);
    const int lb0 = w * 1024, lb1 = w * 1024 + 512;
    const u16* pA0 = Ah + (size_t)(m0 + grow) * 1024 + colx;
    const u16* pA1 = Ah + (size_t)(m0 + grow + 16) * 1024 + colx;
    const u16* pB0 = Bh + (size_t)(n0 + grow) * 1024 + colx;
    const u16* pB1 = Bh + (size_t)(n0 + grow + 16) * 1024 + colx;

    auto stage = [&](u16* SA, u16* SB, int kk) {
        const int ko = kk * 32;
        gl16(pA0 + ko, &SA[lb0]);
        gl16(pA1 + ko, &SA[lb1]);
        gl16(pB0 + ko, &SB[lb0]);
        gl16(pB1 + ko, &SB[lb1]);
    };

    f32x4 acc[4][4];
#pragma unroll
    for (int m = 0; m < 4; ++m)
#pragma unroll
        for (int n = 0; n < 4; ++n) acc[m][n] = (f32x4){0.f, 0.f, 0.f, 0.f};

    auto compute = [&](const u16* SA, const u16* SB) {
        bf16x8 fa[4], fb[4];
#pragma unroll
        for (int m = 0; m < 4; ++m)
            fa[m] = *reinterpret_cast<const bf16x8*>(&SA[SWZ(ar + m * 16, fk)]);
#pragma unroll
        for (int n = 0; n < 4; ++n)
            fb[n] = *reinterpret_cast<const bf16x8*>(&SB[SWZ(br + n * 16, fk)]);
#pragma unroll
        for (int m = 0; m < 4; ++m)
#pragma unroll
            for (int n = 0; n < 4; ++n)
                acc[m][n] = __builtin_amdgcn_mfma_f32_16x16x32_bf16(fa[m], fb[n], acc[m][n], 0, 0, 0);
    };

    stage(sA0, sB0, 0);
    __syncthreads();
    for (int kk = 0; kk < 32; kk += 2) {
        stage(sA1, sB1, kk + 1);
        compute(sA0, sB0);
        __syncthreads();
        if (kk + 2 < 32) stage(sA0, sB0, kk + 2);
        compute(sA1, sB1);
        __syncthreads();
    }

    const int er4 = (l >> 4) * 4;
    float bvv[4];
#pragma unroll
    for (int n = 0; n < 4; ++n) bvv[n] = bias[n0 + wc * 64 + n * 16 + fr];
#pragma unroll
    for (int m = 0; m < 4; ++m)
#pragma unroll
        for (int n = 0; n < 4; ++n) {
            const int col = n0 + wc * 64 + n * 16 + fr;
            const size_t rb = (size_t)(m0 + wr * 64 + m * 16 + er4) * 1024 + col;
#pragma unroll
            for (int r = 0; r < 4; ++r) C[rb + (size_t)r * 1024] = acc[m][n][r] + bvv[n];
        }
}

// ---------------- flash attention (frozen from R16/R17/R18) ---------------
#define SM_M2 17.312340490667562f  // 12 * log2(e)

#define ATTN_TILE(SK, SV)                                                      \
  {                                                                            \
    f32x4 s[2][4];                                                             \
    _Pragma("unroll") for (int qm = 0; qm < 2; ++qm)                           \
      _Pragma("unroll") for (int n = 0; n < 4; ++n)                            \
        s[qm][n] = (f32x4){-SM_M2, -SM_M2, -SM_M2, -SM_M2};                    \
    _Pragma("unroll") for (int n = 0; n < 4; ++n)                              \
      _Pragma("unroll") for (int ks = 0; ks < 2; ++ks) {                       \
        bf16x8 bkh = *reinterpret_cast<const bf16x8*>(                         \
            &SK[(n * 16 + fr) * 64 + ((ks * 32 + fk) ^ rswz)]);                \
        _Pragma("unroll") for (int qm = 0; qm < 2; ++qm)                       \
          s[qm][n] = __builtin_amdgcn_mfma_f32_16x16x32_bf16(aqh[qm][ks], bkh, s[qm][n], 0, 0, 0); \
      }                                                                        \
    _Pragma("unroll") for (int qm = 0; qm < 2; ++qm)                           \
      _Pragma("unroll") for (int n = 0; n < 4; ++n)                            \
        _Pragma("unroll") for (int r = 0; r < 4; ++r) {                        \
          const float p = fast_exp2(s[qm][n][r]);                              \
          const int prow = w * 32 + qm * 16 + (l >> 4) * 4 + r;                \
          const int pcol = (n * 16 + (l & 15)) ^ ((prow & 7) << 3);            \
          sPh[prow * 64 + pcol] = f2bf(p);                                     \
        }                                                                      \
    bf16x8 bph[2][2];                                                          \
    _Pragma("unroll") for (int qm = 0; qm < 2; ++qm)                           \
      _Pragma("unroll") for (int ks = 0; ks < 2; ++ks)                         \
        bph[qm][ks] = *reinterpret_cast<const bf16x8*>(                        \
            &sPh[(w * 32 + qm * 16 + fr) * 64 + ((ks * 32 + fk) ^ rswz)]);     \
    _Pragma("unroll") for (int m = 0; m < 4; ++m)                              \
      _Pragma("unroll") for (int ks = 0; ks < 2; ++ks) {                       \
        bf16x8 avh = *reinterpret_cast<const bf16x8*>(                         \
            &SV[(m * 16 + fr) * 64 + ((ks * 32 + fk) ^ rswz)]);                \
        _Pragma("unroll") for (int qm = 0; qm < 2; ++qm)                       \
          aco[qm][m] = __builtin_amdgcn_mfma_f32_16x16x32_bf16(avh, bph[qm][ks], aco[qm][m], 0, 0, 0); \
      }                                                                        \
    _Pragma("unroll") for (int qm = 0; qm < 2; ++qm)                           \
      _Pragma("unroll") for (int ks = 0; ks < 2; ++ks)                         \
        acl[qm] = __builtin_amdgcn_mfma_f32_16x16x32_bf16(vone, bph[qm][ks], acl[qm], 0, 0, 0); \
  }

#define ATTN_STAGE(SK, SV)                                                     \
  {                                                                            \
    _Pragma("unroll") for (int i = 0; i < 2; ++i) {                            \
      *reinterpret_cast<bf16x8*>(&SK[soff[i]]) = rKh[i];                       \
      *reinterpret_cast<bf16x8*>(&SV[soff[i]]) = rVh[i];                       \
    }                                                                          \
  }

__global__ __launch_bounds__(256) void k_attn(
    const u16* __restrict__ Qh,
    const u16* __restrict__ Kh,
    const u16* __restrict__ VTh,
    u16* __restrict__ AOh) {
    __shared__ __attribute__((aligned(16))) u16 sK0[4096];
    __shared__ __attribute__((aligned(16))) u16 sK1[4096];
    __shared__ __attribute__((aligned(16))) u16 sV0[4096];
    __shared__ __attribute__((aligned(16))) u16 sV1[4096];
    __shared__ __attribute__((aligned(16))) u16 sPh[128 * 64];

    const int t = threadIdx.x;
    const int l = t & 63, w = t >> 6;
    const int flat = blockIdx.y * 16 + blockIdx.x;          // 0..511
    const int tau = (flat & 7) * 64 + (flat >> 3);          // bijective
    const int q0 = (tau & 15) * 128;
    const int bh = tau >> 4;
    const int b = bh >> 4, h = bh & 15;
    const size_t qrow0 = (size_t)b * 2048 + q0;

    const u16* Qb_h = Qh + qrow0 * 1024 + h * 64;
    const u16* Kb_h = Kh + (size_t)b * 2048 * 1024 + h * 64;
    const u16* Vb_h = VTh + (size_t)bh * 64 * 2048;

    const int fr = l & 15;
    const int fk = (l >> 4) * 8;

    bf16x8 aqh[2][2];
#pragma unroll
    for (int qm = 0; qm < 2; ++qm)
#pragma unroll
        for (int ks = 0; ks < 2; ++ks) {
            const size_t qo = (size_t)(w * 32 + qm * 16 + fr) * 1024 + ks * 32 + fk;
            aqh[qm][ks] = g8(Qb_h + qo);
        }

    bf16x8 vone;
#pragma unroll
    for (int j = 0; j < 8; ++j) vone[j] = (short)0x3F80;

    f32x4 aco[2][4];
    f32x4 acl[2];
#pragma unroll
    for (int qm = 0; qm < 2; ++qm) {
        acl[qm] = (f32x4){0.f, 0.f, 0.f, 0.f};
#pragma unroll
        for (int m = 0; m < 4; ++m) aco[qm][m] = (f32x4){0.f, 0.f, 0.f, 0.f};
    }

    const int sr = t >> 3, sc = (t & 7) * 8;  // staging: row sr(+32), col sc
    bf16x8 rKh[2], rVh[2];
    auto load_kv = [&](int tt) {
        const int kv0 = tt * 64;
#pragma unroll
        for (int i = 0; i < 2; ++i) {
            const int r2 = sr + i * 32;
            rKh[i] = g8(Kb_h + (size_t)(kv0 + r2) * 1024 + sc);
            rVh[i] = g8(Vb_h + (size_t)r2 * 2048 + kv0 + sc);
        }
    };
    int soff[2];
#pragma unroll
    for (int i = 0; i < 2; ++i) {
        const int r2 = sr + i * 32;
        soff[i] = r2 * 64 + (sc ^ ((r2 & 7) << 3));
    }
    const int rswz = (fr & 7) << 3;

    load_kv(0);
    ATTN_STAGE(sK0, sV0);
    __syncthreads();

    for (int tt = 0; tt < 32; tt += 2) {
        load_kv(tt + 1);
        ATTN_TILE(sK0, sV0);
        ATTN_STAGE(sK1, sV1);
        __syncthreads();
        if (tt + 2 < 32) load_kv(tt + 2);
        ATTN_TILE(sK1, sV1);
        if (tt + 2 < 32) ATTN_STAGE(sK0, sV0);
        __syncthreads();
    }

#pragma unroll
    for (int qm = 0; qm < 2; ++qm) {
        const float inv = 1.0f / acl[qm][0];
#pragma unroll
        for (int m = 0; m < 4; ++m) aco[qm][m] *= inv;
    }

    // wave-private transpose through the wave's own dead 8KB K/V buffer.
    float* Ol = reinterpret_cast<float*>(
        (w == 0) ? sK0 : (w == 1) ? sK1 : (w == 2) ? sV0 : sV1);
#pragma unroll
    for (int qm = 0; qm < 2; ++qm) {
        const int qr = qm * 16 + (l & 15);
        const int sw = (qr & 7) << 3;
#pragma unroll
        for (int m = 0; m < 4; ++m)
#pragma unroll
            for (int r = 0; r < 4; ++r)
                Ol[qr * 64 + ((m * 16 + (l >> 4) * 4 + r) ^ sw)] = aco[qm][m][r];
    }
#pragma unroll
    for (int it = 0; it < 4; ++it) {
        const int qr = (l >> 3) + it * 8;   // 0..31 within the wave's rows
        const int cb = (l & 7) * 8;
        const int sw = (qr & 7) << 3;
        const float* srcp = &Ol[qr * 64 + (cb ^ sw)];
        u16x8 oh;
#pragma unroll
        for (int j = 0; j < 8; ++j) oh[j] = f2bf(srcp[j]);
        const size_t ob = (qrow0 + w * 32 + qr) * 1024 + h * 64 + cb;
        *reinterpret_cast<u16x8*>(&AOh[ob]) = oh;
    }
}

// ---------------- host ----------------
extern "C" void kernel_launch(void* const* d_in, const int* in_sizes, int n_in,
                              void* d_out, int out_size, void* d_ws, size_t ws_size,
                              hipStream_t stream) {
    const float* q = (const float*)d_in[0];
    const float* k = (const float*)d_in[1];
    const float* v = (const float*)d_in[2];
    const float* Wq = (const float*)d_in[3];
    const float* bq = (const float*)d_in[4];
    const float* Wk = (const float*)d_in[5];
    const float* bk = (const float*)d_in[6];
    const float* Wv = (const float*)d_in[7];
    const float* bv = (const float*)d_in[8];
    const float* Wo = (const float*)d_in[9];
    const float* bo = (const float*)d_in[10];
    const float* phase = (const float*)d_in[11];
    float* out = (float*)d_out;

    char* ws = (char*)d_ws;
    const size_t MB = 1u << 20;
    u16* Wq_h = (u16*)(ws + 0 * MB);
    u16* Wk_h = (u16*)(ws + 2 * MB);
    u16* Wv_h = (u16*)(ws + 4 * MB);
    u16* Wo_h = (u16*)(ws + 6 * MB);
    u16* QR_h = (u16*)(ws + 64 * MB);
    u16* KR_h = (u16*)(ws + 80 * MB);
    u16* VT_h = (u16*)(ws + 96 * MB);
    u16* AO_h = (u16*)(ws + 16 * MB);

    // 1. weight split (small)
    k_splitW<<<dim3(1024, 4), 256, 0, stream>>>(Wq, Wk, Wv, Wo,
                                                Wq_h, Wk_h, Wv_h, Wo_h);
    // 2. fused QKV projections; A from fp32 (write-late), B via gload_lds
    k_gemm<<<dim3(8, 32, 3), 256, 0, stream>>>(
        q, k, v, Wq_h, Wk_h, Wv_h,
        bq, bk, bv, phase, QR_h, KR_h, VT_h);
    // 3. attention (QBLK=128)
    k_attn<<<dim3(16, 32), 256, 0, stream>>>(QR_h, KR_h, VT_h, AO_h);
    // 4. output projection (1-term, full gload_lds)
    k_gemm1<<<dim3(8, 32), 256, 0, stream>>>(AO_h, Wo_h, bo, out);
    (void)in_sizes; (void)n_in; (void)out_size; (void)ws_size;
}